// Round 9
// baseline (53.280 us; speedup 1.0000x reference)
//
#include <hip/hip_runtime.h>

#define EPSILON_F 5.0f

// R9 probe: one 8-row chunk per wave, no grid-stride loop (grid 2048 -> 8192
// blocks). Theory: the 4-iteration loop exposed one L2-gather latency per
// chunk (next chunk's feature burst can't issue until f0-f7 regs free after
// the dependent means gather). Wave-churn replaces software pipelining:
// freshly-dispatched waves in their feature-burst phase overlap draining
// waves stuck in their gather phase.
// Load/reduce body identical to R6/R8 (best known: 48.4 us).
__global__ __launch_bounds__(256) void ncl_partial_kernel(
    const float* __restrict__ feat,     // [B, 256]
    const float* __restrict__ means,    // [C, 256]
    const int* __restrict__ labels,     // [B]
    float* __restrict__ partials)       // [gridDim.x]
{
    const int lane = threadIdx.x & 63;
    const int wave = threadIdx.x >> 6;
    const int gwave = blockIdx.x * (blockDim.x >> 6) + wave;  // == chunk index
    const int grp = lane >> 4;

    const size_t rb = (size_t)gwave * 8;  // first row of this wave's 8-row chunk
    const int4 lva = *reinterpret_cast<const int4*>(labels + rb);
    const int4 lvb = *reinterpret_cast<const int4*>(labels + rb + 4);

    const float* fp = feat + rb * 256 + lane * 4;
    const float4 f0 = *reinterpret_cast<const float4*>(fp);
    const float4 f1 = *reinterpret_cast<const float4*>(fp + 256);
    const float4 f2 = *reinterpret_cast<const float4*>(fp + 512);
    const float4 f3 = *reinterpret_cast<const float4*>(fp + 768);
    const float4 f4 = *reinterpret_cast<const float4*>(fp + 1024);
    const float4 f5 = *reinterpret_cast<const float4*>(fp + 1280);
    const float4 f6 = *reinterpret_cast<const float4*>(fp + 1536);
    const float4 f7 = *reinterpret_cast<const float4*>(fp + 1792);

    const float4 m0 = *reinterpret_cast<const float4*>(means + (size_t)lva.x * 256 + lane * 4);
    const float4 m1 = *reinterpret_cast<const float4*>(means + (size_t)lva.y * 256 + lane * 4);
    const float4 m2 = *reinterpret_cast<const float4*>(means + (size_t)lva.z * 256 + lane * 4);
    const float4 m3 = *reinterpret_cast<const float4*>(means + (size_t)lva.w * 256 + lane * 4);
    const float4 m4 = *reinterpret_cast<const float4*>(means + (size_t)lvb.x * 256 + lane * 4);
    const float4 m5 = *reinterpret_cast<const float4*>(means + (size_t)lvb.y * 256 + lane * 4);
    const float4 m6 = *reinterpret_cast<const float4*>(means + (size_t)lvb.z * 256 + lane * 4);
    const float4 m7 = *reinterpret_cast<const float4*>(means + (size_t)lvb.w * 256 + lane * 4);

    float d0, d1, d2, d3, d4, d5, d6, d7;
    { float x=f0.x-m0.x, y=f0.y-m0.y, z=f0.z-m0.z, w=f0.w-m0.w; d0 = x*x + y*y + z*z + w*w; }
    { float x=f1.x-m1.x, y=f1.y-m1.y, z=f1.z-m1.z, w=f1.w-m1.w; d1 = x*x + y*y + z*z + w*w; }
    { float x=f2.x-m2.x, y=f2.y-m2.y, z=f2.z-m2.z, w=f2.w-m2.w; d2 = x*x + y*y + z*z + w*w; }
    { float x=f3.x-m3.x, y=f3.y-m3.y, z=f3.z-m3.z, w=f3.w-m3.w; d3 = x*x + y*y + z*z + w*w; }
    { float x=f4.x-m4.x, y=f4.y-m4.y, z=f4.z-m4.z, w=f4.w-m4.w; d4 = x*x + y*y + z*z + w*w; }
    { float x=f5.x-m5.x, y=f5.y-m5.y, z=f5.z-m5.z, w=f5.w-m5.w; d5 = x*x + y*y + z*z + w*w; }
    { float x=f6.x-m6.x, y=f6.y-m6.y, z=f6.z-m6.z, w=f6.w-m6.w; d6 = x*x + y*y + z*z + w*w; }
    { float x=f7.x-m7.x, y=f7.y-m7.y, z=f7.z-m7.z, w=f7.w-m7.w; d7 = x*x + y*y + z*z + w*w; }

    // stage 1+2: after these, each lane's d_r = sum over lanes sharing (lane & 15)
    d0 += __shfl_xor(d0, 32, 64); d1 += __shfl_xor(d1, 32, 64);
    d2 += __shfl_xor(d2, 32, 64); d3 += __shfl_xor(d3, 32, 64);
    d4 += __shfl_xor(d4, 32, 64); d5 += __shfl_xor(d5, 32, 64);
    d6 += __shfl_xor(d6, 32, 64); d7 += __shfl_xor(d7, 32, 64);
    d0 += __shfl_xor(d0, 16, 64); d1 += __shfl_xor(d1, 16, 64);
    d2 += __shfl_xor(d2, 16, 64); d3 += __shfl_xor(d3, 16, 64);
    d4 += __shfl_xor(d4, 16, 64); d5 += __shfl_xor(d5, 16, 64);
    d6 += __shfl_xor(d6, 16, 64); d7 += __shfl_xor(d7, 16, 64);

    // 16-lane group g owns row g (first group of 4) and row g+4 (second)
    float xa = (grp == 0) ? d0 : (grp == 1) ? d1 : (grp == 2) ? d2 : d3;
    float xb = (grp == 0) ? d4 : (grp == 1) ? d5 : (grp == 2) ? d6 : d7;

    // shared stages: two independent chains finish 8 rows in 8 DS ops
    xa += __shfl_xor(xa, 8, 64);  xb += __shfl_xor(xb, 8, 64);
    xa += __shfl_xor(xa, 4, 64);  xb += __shfl_xor(xb, 4, 64);
    xa += __shfl_xor(xa, 2, 64);  xb += __shfl_xor(xb, 2, 64);
    xa += __shfl_xor(xa, 1, 64);  xb += __shfl_xor(xb, 1, 64);

    // each row counted 16x across the wave; reduce the wave's hinge sum
    float acc = fmaxf(EPSILON_F - sqrtf(xa), 0.0f)
              + fmaxf(EPSILON_F - sqrtf(xb), 0.0f);
    #pragma unroll
    for (int off = 32; off; off >>= 1) acc += __shfl_xor(acc, off, 64);

    __shared__ float wsum[4];
    if (lane == 0) wsum[wave] = acc * 0.0625f;   // undo the 16x counting
    __syncthreads();
    if (threadIdx.x == 0)
        partials[blockIdx.x] = wsum[0] + wsum[1] + wsum[2] + wsum[3];
}

// Pass 2: deterministic reduce of block partials -> mean.
__global__ __launch_bounds__(256) void ncl_final_kernel(
    const float* __restrict__ partials, int n, float* __restrict__ out, float invB)
{
    float s = 0.0f;
    for (int i = threadIdx.x; i < n; i += 256) s += partials[i];
    #pragma unroll
    for (int off = 32; off; off >>= 1) s += __shfl_xor(s, off, 64);
    __shared__ float wsum[4];
    if ((threadIdx.x & 63) == 0) wsum[threadIdx.x >> 6] = s;
    __syncthreads();
    if (threadIdx.x == 0) out[0] = (wsum[0] + wsum[1] + wsum[2] + wsum[3]) * invB;
}

extern "C" void kernel_launch(void* const* d_in, const int* in_sizes, int n_in,
                              void* d_out, int out_size, void* d_ws, size_t ws_size,
                              hipStream_t stream)
{
    const float* feat   = (const float*)d_in[0];   // [B, 256] f32
    const float* means  = (const float*)d_in[1];   // [C, 256] f32
    const int*   labels = (const int*)d_in[2];     // [B] int
    float* out = (float*)d_out;

    const int B = in_sizes[0] / 256;
    const int NBLOCKS = 8192;                      // B/8 chunks / 4 waves per block
    float* partials = (float*)d_ws;                // 8192 floats = 32 KB scratch

    ncl_partial_kernel<<<NBLOCKS, 256, 0, stream>>>(feat, means, labels, partials);
    ncl_final_kernel<<<1, 256, 0, stream>>>(partials, NBLOCKS, out, 1.0f / (float)B);
}

// Round 10
// 48.572 us; speedup vs baseline: 1.0969x; 1.0969x over previous
//
#include <hip/hip_runtime.h>

#define EPSILON_F 5.0f

// R10 = R8 (best known: 48.4 us) + label prefetch one grid-stride iteration
// ahead. The next chunk's two int4 label loads issue at the TOP of the
// current iteration (no consumer until next iteration -> no waitcnt stall),
// hiding label-load latency under current compute; steady-state dependent
// chain is then only the means L2 gather.
// R7 lesson: no single-counter atomics. R9 lesson: keep the grid-stride loop.
__global__ __launch_bounds__(256) void ncl_partial_kernel(
    const float* __restrict__ feat,     // [B, 256]
    const float* __restrict__ means,    // [C, 256]
    const int* __restrict__ labels,     // [B]
    float* __restrict__ partials,       // [gridDim.x]
    int nchunks)                        // B / 8
{
    const int lane = threadIdx.x & 63;
    const int wave = threadIdx.x >> 6;
    const int gwave = blockIdx.x * (blockDim.x >> 6) + wave;
    const int nwaves = gridDim.x * (blockDim.x >> 6);
    const int grp = lane >> 4;

    float acc = 0.0f;

    int c = gwave;
    int4 lva, lvb;
    if (c < nchunks) {
        lva = *reinterpret_cast<const int4*>(labels + (size_t)c * 8);
        lvb = *reinterpret_cast<const int4*>(labels + (size_t)c * 8 + 4);
    }

    while (c < nchunks) {
        const int cn = c + nwaves;
        // prefetch next iteration's labels first (wave-uniform branch;
        // results unused this iteration -> latency fully hidden)
        int4 nlva, nlvb;
        if (cn < nchunks) {
            nlva = *reinterpret_cast<const int4*>(labels + (size_t)cn * 8);
            nlvb = *reinterpret_cast<const int4*>(labels + (size_t)cn * 8 + 4);
        }

        const size_t rb = (size_t)c * 8;
        const float* fp = feat + rb * 256 + lane * 4;
        const float4 f0 = *reinterpret_cast<const float4*>(fp);
        const float4 f1 = *reinterpret_cast<const float4*>(fp + 256);
        const float4 f2 = *reinterpret_cast<const float4*>(fp + 512);
        const float4 f3 = *reinterpret_cast<const float4*>(fp + 768);
        const float4 f4 = *reinterpret_cast<const float4*>(fp + 1024);
        const float4 f5 = *reinterpret_cast<const float4*>(fp + 1280);
        const float4 f6 = *reinterpret_cast<const float4*>(fp + 1536);
        const float4 f7 = *reinterpret_cast<const float4*>(fp + 1792);

        const float4 m0 = *reinterpret_cast<const float4*>(means + (size_t)lva.x * 256 + lane * 4);
        const float4 m1 = *reinterpret_cast<const float4*>(means + (size_t)lva.y * 256 + lane * 4);
        const float4 m2 = *reinterpret_cast<const float4*>(means + (size_t)lva.z * 256 + lane * 4);
        const float4 m3 = *reinterpret_cast<const float4*>(means + (size_t)lva.w * 256 + lane * 4);
        const float4 m4 = *reinterpret_cast<const float4*>(means + (size_t)lvb.x * 256 + lane * 4);
        const float4 m5 = *reinterpret_cast<const float4*>(means + (size_t)lvb.y * 256 + lane * 4);
        const float4 m6 = *reinterpret_cast<const float4*>(means + (size_t)lvb.z * 256 + lane * 4);
        const float4 m7 = *reinterpret_cast<const float4*>(means + (size_t)lvb.w * 256 + lane * 4);

        float d0, d1, d2, d3, d4, d5, d6, d7;
        { float x=f0.x-m0.x, y=f0.y-m0.y, z=f0.z-m0.z, w=f0.w-m0.w; d0 = x*x + y*y + z*z + w*w; }
        { float x=f1.x-m1.x, y=f1.y-m1.y, z=f1.z-m1.z, w=f1.w-m1.w; d1 = x*x + y*y + z*z + w*w; }
        { float x=f2.x-m2.x, y=f2.y-m2.y, z=f2.z-m2.z, w=f2.w-m2.w; d2 = x*x + y*y + z*z + w*w; }
        { float x=f3.x-m3.x, y=f3.y-m3.y, z=f3.z-m3.z, w=f3.w-m3.w; d3 = x*x + y*y + z*z + w*w; }
        { float x=f4.x-m4.x, y=f4.y-m4.y, z=f4.z-m4.z, w=f4.w-m4.w; d4 = x*x + y*y + z*z + w*w; }
        { float x=f5.x-m5.x, y=f5.y-m5.y, z=f5.z-m5.z, w=f5.w-m5.w; d5 = x*x + y*y + z*z + w*w; }
        { float x=f6.x-m6.x, y=f6.y-m6.y, z=f6.z-m6.z, w=f6.w-m6.w; d6 = x*x + y*y + z*z + w*w; }
        { float x=f7.x-m7.x, y=f7.y-m7.y, z=f7.z-m7.z, w=f7.w-m7.w; d7 = x*x + y*y + z*z + w*w; }

        // stage 1+2: after these, each lane's d_r = sum over lanes sharing (lane & 15)
        d0 += __shfl_xor(d0, 32, 64); d1 += __shfl_xor(d1, 32, 64);
        d2 += __shfl_xor(d2, 32, 64); d3 += __shfl_xor(d3, 32, 64);
        d4 += __shfl_xor(d4, 32, 64); d5 += __shfl_xor(d5, 32, 64);
        d6 += __shfl_xor(d6, 32, 64); d7 += __shfl_xor(d7, 32, 64);
        d0 += __shfl_xor(d0, 16, 64); d1 += __shfl_xor(d1, 16, 64);
        d2 += __shfl_xor(d2, 16, 64); d3 += __shfl_xor(d3, 16, 64);
        d4 += __shfl_xor(d4, 16, 64); d5 += __shfl_xor(d5, 16, 64);
        d6 += __shfl_xor(d6, 16, 64); d7 += __shfl_xor(d7, 16, 64);

        // 16-lane group g owns row g (first group of 4) and row g+4 (second)
        float xa = (grp == 0) ? d0 : (grp == 1) ? d1 : (grp == 2) ? d2 : d3;
        float xb = (grp == 0) ? d4 : (grp == 1) ? d5 : (grp == 2) ? d6 : d7;

        // shared stages: two independent chains finish 8 rows in 8 DS ops
        xa += __shfl_xor(xa, 8, 64);  xb += __shfl_xor(xb, 8, 64);
        xa += __shfl_xor(xa, 4, 64);  xb += __shfl_xor(xb, 4, 64);
        xa += __shfl_xor(xa, 2, 64);  xb += __shfl_xor(xb, 2, 64);
        xa += __shfl_xor(xa, 1, 64);  xb += __shfl_xor(xb, 1, 64);

        // each row counted 16x (corrected by 1/16 at the end)
        acc += fmaxf(EPSILON_F - sqrtf(xa), 0.0f)
             + fmaxf(EPSILON_F - sqrtf(xb), 0.0f);

        lva = nlva; lvb = nlvb;
        c = cn;
    }

    // wave-reduce acc once per kernel (rows were counted 16x -> scale 1/16)
    #pragma unroll
    for (int off = 32; off; off >>= 1) acc += __shfl_xor(acc, off, 64);

    __shared__ float wsum[4];
    if (lane == 0) wsum[wave] = acc * 0.0625f;
    __syncthreads();
    if (threadIdx.x == 0)
        partials[blockIdx.x] = wsum[0] + wsum[1] + wsum[2] + wsum[3];
}

// Pass 2: deterministic reduce of block partials -> mean.
__global__ __launch_bounds__(256) void ncl_final_kernel(
    const float* __restrict__ partials, int n, float* __restrict__ out, float invB)
{
    float s = 0.0f;
    for (int i = threadIdx.x; i < n; i += 256) s += partials[i];
    #pragma unroll
    for (int off = 32; off; off >>= 1) s += __shfl_xor(s, off, 64);
    __shared__ float wsum[4];
    if ((threadIdx.x & 63) == 0) wsum[threadIdx.x >> 6] = s;
    __syncthreads();
    if (threadIdx.x == 0) out[0] = (wsum[0] + wsum[1] + wsum[2] + wsum[3]) * invB;
}

extern "C" void kernel_launch(void* const* d_in, const int* in_sizes, int n_in,
                              void* d_out, int out_size, void* d_ws, size_t ws_size,
                              hipStream_t stream)
{
    const float* feat   = (const float*)d_in[0];   // [B, 256] f32
    const float* means  = (const float*)d_in[1];   // [C, 256] f32
    const int*   labels = (const int*)d_in[2];     // [B] int
    float* out = (float*)d_out;

    const int B = in_sizes[0] / 256;
    const int NBLOCKS = 2048;
    float* partials = (float*)d_ws;  // 2048 floats = 8 KB scratch

    ncl_partial_kernel<<<NBLOCKS, 256, 0, stream>>>(feat, means, labels, partials, B / 8);
    ncl_final_kernel<<<1, 256, 0, stream>>>(partials, NBLOCKS, out, 1.0f / (float)B);
}